// Round 8
// baseline (448.533 us; speedup 1.0000x reference)
//
#include <hip/hip_runtime.h>
#include <hip/hip_bf16.h>

#define FDIM 60
#define MROW 600
#define CDIM 8
#define ODIM 18
#define CH   120
#define NCHUNK 5
#define BLK  512
#define NBLK 768   // persistent grid: 3 blocks/CU x 256 CU

typedef short bf16x8 __attribute__((ext_vector_type(8)));
typedef float f32x4  __attribute__((ext_vector_type(4)));

// RNE pack two fp32 -> bf16x2 via v_cvt_pk_bf16_f32 (lo = low half, hi = high half)
__device__ __forceinline__ unsigned int pk2(float lo, float hi) {
    __hip_bfloat162 h2 = __float22bfloat162_rn(make_float2(lo, hi));
    unsigned int u;
    __builtin_memcpy(&u, &h2, sizeof(u));
    return u;
}
__device__ __forceinline__ short f2bf(float f) {
    __hip_bfloat16 h = __float2bfloat16(f);
    short s;
    __builtin_memcpy(&s, &h, sizeof(s));
    return s;
}

// wave-local LDS drain (producer->consumer within one wave) + scheduler fence
#define WAVE_LGKM() do {                                          \
    asm volatile("s_waitcnt lgkmcnt(0)" ::: "memory");            \
    __builtin_amdgcn_sched_barrier(0);                            \
} while (0)
// raw barrier: drains LDS only, NOT vmcnt -> prefetch loads stay in flight
// (all epilogue global reads are register-consumed; compiler inserts its own
//  vmcnt waits at the use points)
#define RAW_BAR() do {                                            \
    asm volatile("s_waitcnt lgkmcnt(0)" ::: "memory");            \
    __builtin_amdgcn_s_barrier();                                 \
    __builtin_amdgcn_sched_barrier(0);                            \
} while (0)

__global__ void __launch_bounds__(BLK, 6) netfv_kernel(
    const float* __restrict__ x,      // [B*M, F] fp32
    const float* __restrict__ W,      // [F, C]
    const float* __restrict__ covar,  // [F, C]
    const float* __restrict__ bias,   // [C]
    const float* __restrict__ cw2,    // [1, F, C]
    const float* __restrict__ H,      // [2*C*F, OUT]
    float* __restrict__ out,          // [B, OUT]
    int Bn)
{
    // LDS: 17408 + 17280 + 4352 + 2304 = 41,344 B -> 3 blocks/CU.
    __shared__ __align__(16) short xsT1[64 * 136];   // x [f][m] k-major, swizzled
    __shared__ __align__(16) short xsM [120 * 72];   // x [m][f] m-major
    __shared__ __align__(16) short actT[16 * 136];   // act [c][m] k-major (c>=8 zero)
    __shared__ __align__(16) short WtB [16 * 72];    // W^T bf16 (c>=8 / f>=60 zero)

    // epilogue overlays (used only after the K-loop's final RAW_BAR).
    // Audited: corrupted actT region (rows 0..3, cols<=135) is either
    // rewritten by logits each chunk (cols<128) or never read by einsum
    // (cols 128..135). xsT1 ints 0..1983 re-zeroed between batches.
    float* const fvbuf = (float*)xsT1;          // 1024 f
    float* const fvl   = (float*)xsT1 + 1024;   // 960 f
    float* const redA  = (float*)actT;          // 64 f
    float* const redB  = redA + 64;             // 64 f
    float* const asuml = redB + 64;             // 8 f
    float* const n1rs  = asuml + 8;             // 8 f
    float* const n1c_s = n1rs + 8;              // 8 f
    float* const n2c_s = n1c_s + 8;             // 8 f
    float* const scal  = n2c_s + 8;             // 2 f

    const int tid  = threadIdx.x;
    const int lane = tid & 63;
    const int wv   = tid >> 6;
    const int mg   = tid >> 3;      // row-pair 0..63 (0..59 active)
    const int fs   = tid & 7;       // f-slice (8 floats)
    const int ln15 = lane & 15;
    const int quad = lane >> 4;
    const int fvsel = wv & 1;       // 0: fv1 (x), 1: fv2 (x^2, squared in-reg)
    const int tile  = wv >> 1;      // f-tile 0..3

    const bool stv = (mg < 60);     // staging-valid (loop-invariant: 600 = 5*120)
    const int xoff = 2 * mg * FDIM + 8 * fs;  // within-batch staging offset
    const int mloc = wv * 16 + ln15;          // local m in logits phase
    const bool vm = (mloc < CH);              // rows 120..127 dead
    const int mrow = vm ? mloc : 0;           // clamped xsM read row

    int nb = blockIdx.x;            // first batch for this persistent block

    // ---- preload chunk 0 of first batch (overlaps with init) ----
    float4 A0, A1, B0, B1;
    A0 = A1 = B0 = B1 = make_float4(0.f, 0.f, 0.f, 0.f);
    if (nb < Bn && stv) {
        const float* p0 = x + (size_t)nb * (MROW * FDIM) + xoff;
        A0 = *(const float4*)p0;
        A1 = *(const float4*)(p0 + FDIM);
        if (fs < 7) { B0 = *(const float4*)(p0 + 4); B1 = *(const float4*)(p0 + FDIM + 4); }
    }

    // --- one-time init (amortized over all batches of this block) ---
    {
        int c = tid >> 5, j = tid & 31;
        float v0 = (2 * j     < FDIM) ? W[(2 * j) * CDIM + (c & 7)]     : 0.f;
        float v1 = (2 * j + 1 < FDIM) ? W[(2 * j + 1) * CDIM + (c & 7)] : 0.f;
        if (c >= CDIM) { v0 = 0.f; v1 = 0.f; }
        ((unsigned int*)WtB)[c * 36 + j] = pk2(v0, v1);
    }
    {
        unsigned int* z1 = (unsigned int*)xsT1;
        for (int i = tid; i < 64 * 68; i += BLK) z1[i] = 0u;
        unsigned int* az = (unsigned int*)(actT + 8 * 136);
        for (int i = tid; i < 544; i += BLK) az[i] = 0u;
    }
    __syncthreads();   // init visible (once per block lifetime)

    // hoisted W A-fragments + bias fragment (persist across batches)
    const bf16x8 aw0 = *(const bf16x8*)(WtB + ln15 * 72 + quad * 8);
    const bf16x8 aw1 = *(const bf16x8*)(WtB + ln15 * 72 + 32 + quad * 8);
    const float4 lb  = *(const float4*)(bias + (quad & 1) * 4);

    while (nb < Bn) {
        const int nbn = nb + NBLK;          // next batch (static stride)
        const float* prow = x + (size_t)nb * (MROW * FDIM) + xoff;

        f32x4 acc = {0.f, 0.f, 0.f, 0.f};
        float asum_acc[4] = {0.f, 0.f, 0.f, 0.f};

        for (int ck = 0; ck < NCHUNK; ++ck) {
            // --- stage current chunk: xsM (m-major b128) + xsT1 (swizzled) ---
            if (stv) {
                float xv0[8] = {A0.x, A0.y, A0.z, A0.w, B0.x, B0.y, B0.z, B0.w};
                float xv1[8] = {A1.x, A1.y, A1.z, A1.w, B1.x, B1.y, B1.z, B1.w};
                {
                    unsigned int q0 = pk2(xv0[0], xv0[1]), q1 = pk2(xv0[2], xv0[3]);
                    unsigned int q2 = pk2(xv0[4], xv0[5]), q3 = pk2(xv0[6], xv0[7]);
                    *(uint4*)(xsM + (2 * mg) * 72 + 8 * fs) = make_uint4(q0, q1, q2, q3);
                    unsigned int s0 = pk2(xv1[0], xv1[1]), s1 = pk2(xv1[2], xv1[3]);
                    unsigned int s2 = pk2(xv1[4], xv1[5]), s3 = pk2(xv1[6], xv1[7]);
                    *(uint4*)(xsM + (2 * mg + 1) * 72 + 8 * fs) = make_uint4(s0, s1, s2, s3);
                }
                const int wbase = (((mg >> 2) ^ fs) << 2) + (mg & 3);
                #pragma unroll
                for (int i = 0; i < 8; ++i) {
                    int woff = (8 * fs + i) * 68 + wbase;
                    ((unsigned int*)xsT1)[woff] = pk2(xv0[i], xv1[i]);
                }
            }
            __builtin_amdgcn_sched_barrier(0);   // pin: pack above, prefetch below

            // --- prefetch: next chunk, or chunk 0 of the NEXT BATCH at ck==4.
            //     Floats across logits+einsum (+ the whole epilogue for the
            //     batch-crossing case: all barriers below are lgkm-only) ---
            float4 nA0, nA1, nB0, nB1;
            nA0 = nA1 = nB0 = nB1 = make_float4(0.f, 0.f, 0.f, 0.f);
            if (stv) {
                if (ck + 1 < NCHUNK) {
                    const float* pn = prow + (size_t)(ck + 1) * (CH * FDIM);
                    nA0 = *(const float4*)pn;
                    nA1 = *(const float4*)(pn + FDIM);
                    if (fs < 7) { nB0 = *(const float4*)(pn + 4); nB1 = *(const float4*)(pn + FDIM + 4); }
                } else if (nbn < Bn) {
                    const float* pn = x + (size_t)nbn * (MROW * FDIM) + xoff;
                    nA0 = *(const float4*)pn;
                    nA1 = *(const float4*)(pn + FDIM);
                    if (fs < 7) { nB0 = *(const float4*)(pn + 4); nB1 = *(const float4*)(pn + FDIM + 4); }
                }
            }

            // --- logits: intra-wave consumer of xsM -> wave-local lgkm wait ---
            WAVE_LGKM();
            {
                bf16x8 bv0 = *(const bf16x8*)(xsM + mrow * 72 + quad * 8);
                bf16x8 bv1 = *(const bf16x8*)(xsM + mrow * 72 + 32 + quad * 8);
                f32x4 lz = {0.f, 0.f, 0.f, 0.f};
                lz = __builtin_amdgcn_mfma_f32_16x16x32_bf16(aw0, bv0, lz, 0, 0, 0);
                lz = __builtin_amdgcn_mfma_f32_16x16x32_bf16(aw1, bv1, lz, 0, 0, 0);
                float L0 = lz[0] + lb.x, L1 = lz[1] + lb.y;
                float L2 = lz[2] + lb.z, L3 = lz[3] + lb.w;
                float mx = fmaxf(fmaxf(L0, L1), fmaxf(L2, L3));
                mx = fmaxf(mx, __shfl_xor(mx, 16));
                float e0 = __expf(L0 - mx), e1 = __expf(L1 - mx);
                float e2 = __expf(L2 - mx), e3 = __expf(L3 - mx);
                float s = e0 + e1 + e2 + e3;
                s += __shfl_xor(s, 16);
                float inv = __builtin_amdgcn_rcpf(s);
                if (quad < 2) {
                    float a0  = vm ? e0 * inv : 0.f, a1v = vm ? e1 * inv : 0.f;
                    float a2v = vm ? e2 * inv : 0.f, a3v = vm ? e3 * inv : 0.f;
                    asum_acc[0] += a0;  asum_acc[1] += a1v;
                    asum_acc[2] += a2v; asum_acc[3] += a3v;
                    actT[(quad * 4 + 0) * 136 + mloc] = f2bf(a0);
                    actT[(quad * 4 + 1) * 136 + mloc] = f2bf(a1v);
                    actT[(quad * 4 + 2) * 136 + mloc] = f2bf(a2v);
                    actT[(quad * 4 + 3) * 136 + mloc] = f2bf(a3v);
                }
            }
            RAW_BAR();   // B2: xsT1 + actT visible to all waves (no vmcnt drain)

            // --- einsum MFMA: 4 K-steps; fv2 waves square bf16 x in-register ---
            {
                const int f   = tile * 16 + ln15;
                const int fsw = f >> 3;
                #pragma unroll
                for (int ks = 0; ks < 4; ++ks) {
                    bf16x8 av = *(const bf16x8*)(actT + ln15 * 136 + ks * 32 + quad * 8);
                    int kblk = ks * 4 + quad;
                    bf16x8 bv = *(const bf16x8*)(xsT1 + f * 136 + ((kblk ^ fsw) << 3));
                    if (fvsel) {
                        union { bf16x8 v; unsigned short us[8]; unsigned int u[4]; } in, sq;
                        in.v = bv;
                        #pragma unroll
                        for (int p = 0; p < 4; ++p) {
                            float lo = __uint_as_float((unsigned)in.us[2 * p]     << 16);
                            float hi = __uint_as_float((unsigned)in.us[2 * p + 1] << 16);
                            sq.u[p] = pk2(lo * lo, hi * hi);
                        }
                        bv = sq.v;
                    }
                    acc = __builtin_amdgcn_mfma_f32_16x16x32_bf16(av, bv, acc, 0, 0, 0);
                }
            }
            RAW_BAR();   // B3: xsT1/xsM/actT consumed; next chunk may overwrite

            A0 = nA0; A1 = nA1; B0 = nB0; B1 = nB1;
        }

        // ---------- a_sum reduce ----------
        #pragma unroll
        for (int r = 0; r < 4; ++r) {
            float v = asum_acc[r];
            v += __shfl_xor(v, 1); v += __shfl_xor(v, 2);
            v += __shfl_xor(v, 4); v += __shfl_xor(v, 8);
            asum_acc[r] = v;
        }
        if (quad < 2 && ln15 == 0) {
            #pragma unroll
            for (int r = 0; r < 4; ++r) redA[wv * 8 + quad * 4 + r] = asum_acc[r];
        }
        RAW_BAR();
        if (tid < 64) {
            float v = redA[tid];
            v += __shfl_down(v, 8); v += __shfl_down(v, 16); v += __shfl_down(v, 32);
            if (tid < 8) asuml[tid] = v;
        }
        // ---------- store MFMA tiles: col=ln15 (f), row=quad*4+reg (c) ----------
        if (quad < 2) {
            #pragma unroll
            for (int r = 0; r < 4; ++r)
                fvbuf[fvsel * 512 + (tile * 16 + ln15) * 8 + quad * 4 + r] = acc[r];
        }
        RAW_BAR();

        // ---------- epilogue math ----------
        float fv1v = 0.f, fv2v = 0.f;
        const int f_e = tid >> 3, c_e = tid & 7;
        if (tid < 480) {
            float fv1r = fvbuf[f_e * 8 + c_e];
            float fv2r = fvbuf[512 + f_e * 8 + c_e];
            float asv  = asuml[c_e];
            float cw2v = cw2[f_e * 8 + c_e];
            float cv   = covar[f_e * 8 + c_e];
            float cwv  = cv * cv + 1e-6f;
            float rcw  = 1.0f / cwv;
            fv1v = (fv1r - asv * cw2v) * rcw;
            fv2v = (fmaf(asv * cw2v, cw2v, fv2r) - 2.0f * fv1r * cw2v) * rcw * rcw - asv;
        }

        // ---------- norm reductions ----------
        {
            float p1 = fv1v * fv1v, p2 = fv2v * fv2v;
            p1 += __shfl_down(p1, 8);  p2 += __shfl_down(p2, 8);
            p1 += __shfl_down(p1, 16); p2 += __shfl_down(p2, 16);
            p1 += __shfl_down(p1, 32); p2 += __shfl_down(p2, 32);
            if (lane < 8) { redA[wv * 8 + lane] = p1; redB[wv * 8 + lane] = p2; }
        }
        RAW_BAR();
        if (tid < 64) {
            float q1 = redA[tid], q2 = redB[tid];
            q1 += __shfl_down(q1, 8);  q2 += __shfl_down(q2, 8);
            q1 += __shfl_down(q1, 16); q2 += __shfl_down(q2, 16);
            q1 += __shfl_down(q1, 32); q2 += __shfl_down(q2, 32);
            if (tid < 8) { n1c_s[tid] = q1; n2c_s[tid] = q2; }
        }
        RAW_BAR();
        if (tid == 0) {
            float S1 = 0.f, S2 = 0.f;
            #pragma unroll
            for (int c = 0; c < 8; ++c) {
                float rs = rsqrtf(fmaxf(n1c_s[c], 1e-12f));
                n1rs[c] = rs;
                S1 += n1c_s[c] * rs * rs;
                S2 += n2c_s[c];
            }
            scal[0] = rsqrtf(fmaxf(S1, 1e-12f));
            scal[1] = rsqrtf(fmaxf(S2, 1e-12f));
        }
        RAW_BAR();
        if (tid < 480) {
            fvl[f_e * 8 + c_e]       = fv1v * n1rs[c_e] * scal[0];
            fvl[480 + f_e * 8 + c_e] = fv2v * scal[1];
        }
        RAW_BAR();

        // ---------- GEMV: out[o] = fv . H[:, o] (H is L2-hot) ----------
        for (int o = wv; o < ODIM; o += 8) {
            float sacc = 0.f;
            #pragma unroll 5
            for (int i = lane; i < 960; i += 64)
                sacc = fmaf(fvl[i], H[i * ODIM + o], sacc);
            sacc += __shfl_down(sacc, 32);
            sacc += __shfl_down(sacc, 16);
            sacc += __shfl_down(sacc, 8);
            sacc += __shfl_down(sacc, 4);
            sacc += __shfl_down(sacc, 2);
            sacc += __shfl_down(sacc, 1);
            if (lane == 0) out[(size_t)nb * ODIM + o] = sacc;
        }

        // ---------- restore xsT1 overlay span (dead octets must be 0) ----------
        RAW_BAR();   // fvl/fvbuf reads done
        {
            unsigned int* z1 = (unsigned int*)xsT1;
            for (int i = tid; i < 1984; i += BLK) z1[i] = 0u;
        }
        RAW_BAR();   // zeros visible before next batch's staging/einsum

        nb = nbn;
    }
}

extern "C" void kernel_launch(void* const* d_in, const int* in_sizes, int n_in,
                              void* d_out, int out_size, void* d_ws, size_t ws_size,
                              hipStream_t stream) {
    const float* x     = (const float*)d_in[0];
    const float* W     = (const float*)d_in[1];
    const float* covar = (const float*)d_in[2];
    const float* bias  = (const float*)d_in[3];
    const float* cw2   = (const float*)d_in[4];
    const float* H     = (const float*)d_in[5];
    float* outp = (float*)d_out;

    const int Bn = in_sizes[0] / (MROW * FDIM);   // 2048
    const int grid = (Bn < NBLK) ? Bn : NBLK;
    hipLaunchKernelGGL(netfv_kernel, dim3(grid), dim3(BLK), 0, stream,
                       x, W, covar, bias, cw2, H, outp, Bn);
}